// Round 1
// baseline (858.349 us; speedup 1.0000x reference)
//
#include <hip/hip_runtime.h>
#include <math.h>

#define DIMM 128
#define NHEAD 8

// ---------------------------------------------------------------------------
// Kernel 1: h1 = h @ W_in + b_in   (and attn_u = h1@Wu+bu, attn_v = h1@Wv)
// block = 256 threads, 16 rows per block
// ---------------------------------------------------------------------------
__global__ __launch_bounds__(256) void k_h1(
        const float* __restrict__ h,
        const float* __restrict__ W_in, const float* __restrict__ b_in,
        const float* __restrict__ Wu, const float* __restrict__ bu,
        const float* __restrict__ Wv,
        float* __restrict__ comb,      // [N][256], h1 goes to cols 0..127
        float* __restrict__ attn_u, float* __restrict__ attn_v,
        int N)
{
    __shared__ float h_lds[16][128];
    __shared__ float h1_lds[16][130];
    int t = threadIdx.x;
    int row0 = blockIdx.x * 16;

    // load 16x128 tile of h (2048 floats = 512 float4, 2 per thread)
    #pragma unroll
    for (int u = 0; u < 2; ++u) {
        int idx = t + u * 256;
        int r = idx >> 5;          // 32 float4 per row
        int c4 = idx & 31;
        float4 v = make_float4(0.f, 0.f, 0.f, 0.f);
        if (row0 + r < N) v = *(const float4*)(h + (size_t)(row0 + r) * DIMM + c4 * 4);
        *(float4*)&h_lds[r][c4 * 4] = v;
    }
    __syncthreads();

    int col = t & 127;
    int rgrp = t >> 7;  // 0..1 -> rows rgrp*8 .. rgrp*8+7
    float acc[8];
    float bi = b_in[col];
    #pragma unroll
    for (int i = 0; i < 8; ++i) acc[i] = bi;
    for (int k = 0; k < 128; ++k) {
        float w = W_in[k * DIMM + col];
        #pragma unroll
        for (int i = 0; i < 8; ++i) acc[i] += h_lds[rgrp * 8 + i][k] * w;
    }
    #pragma unroll
    for (int i = 0; i < 8; ++i) {
        int r = rgrp * 8 + i;
        h1_lds[r][col] = acc[i];
        if (row0 + r < N) comb[(size_t)(row0 + r) * 256 + col] = acc[i];
    }
    __syncthreads();

    // attn projections: 16 rows x (8 u + 8 v) = 256 outputs, 1 per thread
    {
        int r = t >> 4;
        int j = t & 15;
        int head = j & 7;
        bool isv = (j >= 8);
        const float* W = isv ? Wv : Wu;
        float a = isv ? 0.f : bu[head];
        for (int k = 0; k < 128; ++k) a += h1_lds[r][k] * W[k * NHEAD + head];
        if (row0 + r < N) {
            if (isv) attn_v[(size_t)(row0 + r) * NHEAD + head] = a;
            else     attn_u[(size_t)(row0 + r) * NHEAD + head] = a;
        }
    }
}

// ---------------------------------------------------------------------------
// CSR build: histogram -> scan -> scatter
// ---------------------------------------------------------------------------
__global__ void k_hist(const int* __restrict__ dst, int* __restrict__ counts, int E) {
    int e = blockIdx.x * blockDim.x + threadIdx.x;
    if (e < E) atomicAdd(&counts[dst[e]], 1);
}

__global__ __launch_bounds__(1024) void k_scan(
        const int* __restrict__ counts,
        int* __restrict__ row_ptr, int* __restrict__ cursor, int N, int E)
{
    __shared__ int wsum[16];
    int t = threadIdx.x;
    int chunk = (N + 1023) / 1024;
    int s = t * chunk;
    int epos = min(s + chunk, N);
    int local = 0;
    for (int i = s; i < epos; ++i) local += counts[i];

    int lane = t & 63, w = t >> 6;
    int incl = local;
    #pragma unroll
    for (int d = 1; d < 64; d <<= 1) {
        int v = __shfl_up(incl, d, 64);
        if (lane >= d) incl += v;
    }
    if (lane == 63) wsum[w] = incl;
    __syncthreads();
    if (t == 0) {
        int run = 0;
        #pragma unroll
        for (int i = 0; i < 16; ++i) { int v = wsum[i]; wsum[i] = run; run += v; }
    }
    __syncthreads();
    int run = wsum[w] + incl - local;   // exclusive prefix for this thread
    for (int i = s; i < epos; ++i) {
        row_ptr[i] = run;
        cursor[i] = run;
        run += counts[i];
    }
    if (t == 1023) row_ptr[N] = E;
}

__global__ void k_scatter(const int* __restrict__ src, const int* __restrict__ dst,
                          int* __restrict__ cursor, int* __restrict__ src_sorted, int E) {
    int e = blockIdx.x * blockDim.x + threadIdx.x;
    if (e < E) {
        int d = dst[e];
        int p = atomicAdd(&cursor[d], 1);
        src_sorted[p] = src[e];
    }
}

// ---------------------------------------------------------------------------
// Kernel: per-dst-node online softmax + message aggregation
// one wave (64 lanes) per node; lane l owns dims {l, l+64}, both head l&7
// ---------------------------------------------------------------------------
__device__ __forceinline__ float select8(const float v[8], int h) {
    float a = (h & 1) ? v[1] : v[0];
    float b = (h & 1) ? v[3] : v[2];
    float c = (h & 1) ? v[5] : v[4];
    float d = (h & 1) ? v[7] : v[6];
    float e = (h & 2) ? b : a;
    float f = (h & 2) ? d : c;
    return (h & 4) ? f : e;
}

__global__ __launch_bounds__(256) void k_agg(
        const float* __restrict__ comb_h1,   // comb base; h1 = cols 0..127
        const float* __restrict__ attn_u, const float* __restrict__ attn_v,
        const int* __restrict__ row_ptr, const int* __restrict__ src_sorted,
        float* __restrict__ comb,            // msg written to cols 128..255
        int N)
{
    __shared__ float p_lds[4][64][8];
    __shared__ int   s_lds[4][64];
    int t = threadIdx.x;
    int w = t >> 6, lane = t & 63;
    int n = blockIdx.x * 4 + w;
    if (n >= N) return;
    int rs = row_ptr[n], re = row_ptr[n + 1];
    int deg = re - rs;
    float* msg_out = comb + (size_t)n * 256 + 128;
    if (deg == 0) {
        msg_out[lane] = 0.f;
        msg_out[64 + lane] = 0.f;
        return;
    }

    float av[8];
    {
        float4 a0 = *(const float4*)(attn_v + (size_t)n * 8);
        float4 a1 = *(const float4*)(attn_v + (size_t)n * 8 + 4);
        av[0] = a0.x; av[1] = a0.y; av[2] = a0.z; av[3] = a0.w;
        av[4] = a1.x; av[5] = a1.y; av[6] = a1.z; av[7] = a1.w;
    }
    int hsel = lane & 7;
    float m[8];
    #pragma unroll
    for (int hh = 0; hh < 8; ++hh) m[hh] = -3.0e38f;
    float m_sel = -3.0e38f, den_sel = 0.f, acc0 = 0.f, acc1 = 0.f;

    for (int base = 0; base < deg; base += 64) {
        int nact = min(64, deg - base);
        bool act = (lane < nact);
        int sn = act ? src_sorted[rs + base + lane] : 0;
        float sc[8];
        if (act) {
            float4 a0 = *(const float4*)(attn_u + (size_t)sn * 8);
            float4 a1 = *(const float4*)(attn_u + (size_t)sn * 8 + 4);
            float au[8] = {a0.x, a0.y, a0.z, a0.w, a1.x, a1.y, a1.z, a1.w};
            #pragma unroll
            for (int hh = 0; hh < 8; ++hh) {
                float v = au[hh] + av[hh];
                sc[hh] = (v >= 0.f) ? v : 0.2f * v;
            }
        } else {
            #pragma unroll
            for (int hh = 0; hh < 8; ++hh) sc[hh] = -3.0e38f;
        }
        // chunk max per head (butterfly over 64 lanes)
        float cm[8];
        #pragma unroll
        for (int hh = 0; hh < 8; ++hh) cm[hh] = sc[hh];
        #pragma unroll
        for (int d = 1; d < 64; d <<= 1) {
            #pragma unroll
            for (int hh = 0; hh < 8; ++hh)
                cm[hh] = fmaxf(cm[hh], __shfl_xor(cm[hh], d, 64));
        }
        float mn[8], p[8];
        #pragma unroll
        for (int hh = 0; hh < 8; ++hh) {
            mn[hh] = fmaxf(m[hh], cm[hh]);
            p[hh] = expf(sc[hh] - mn[hh]);   // inactive: exp(-huge) = 0
        }
        float csum[8];
        #pragma unroll
        for (int hh = 0; hh < 8; ++hh) csum[hh] = p[hh];
        #pragma unroll
        for (int d = 1; d < 64; d <<= 1) {
            #pragma unroll
            for (int hh = 0; hh < 8; ++hh)
                csum[hh] += __shfl_xor(csum[hh], d, 64);
        }
        float mn_sel = select8(mn, hsel);
        float scale_sel = expf(m_sel - mn_sel);  // first chunk: exp(-huge)=0
        float csum_sel = select8(csum, hsel);
        den_sel = den_sel * scale_sel + csum_sel;
        m_sel = mn_sel;
        #pragma unroll
        for (int hh = 0; hh < 8; ++hh) m[hh] = mn[hh];

        // stash p and src for cross-lane consumption (same wave, LDS in-order)
        #pragma unroll
        for (int hh = 0; hh < 8; ++hh) p_lds[w][lane][hh] = p[hh];
        s_lds[w][lane] = sn;
        __threadfence_block();

        acc0 *= scale_sel;
        acc1 *= scale_sel;
        for (int j = 0; j < nact; ++j) {
            int sj = s_lds[w][j];
            float pj = p_lds[w][j][hsel];
            const float* hr = comb_h1 + (size_t)sj * 256;
            acc0 = fmaf(pj, hr[lane], acc0);
            acc1 = fmaf(pj, hr[64 + lane], acc1);
        }
    }
    float inv = 1.0f / den_sel;
    msg_out[lane] = acc0 * inv;
    msg_out[64 + lane] = acc1 * inv;
}

// ---------------------------------------------------------------------------
// Kernel: fused FF  out = gelu([h1|msg] @ W1 + b1) @ W2 + b2
// block = 256 threads, 32 rows; 4x4 register micro-tiles; hidden in 4 chunks
// ---------------------------------------------------------------------------
__device__ __forceinline__ float gelu_exact(float x) {
    return 0.5f * x * (1.0f + erff(x * 0.70710678118654752f));
}

__global__ __launch_bounds__(256) void k_ff(
        const float* __restrict__ comb,
        const float* __restrict__ W1, const float* __restrict__ b1,
        const float* __restrict__ W2, const float* __restrict__ b2,
        float* __restrict__ out, int N)
{
    __shared__ float c_lds[32][260];   // padded: bank = (4r + k) % 32
    __shared__ float x_lds[32][132];
    int t = threadIdx.x;
    int row0 = blockIdx.x * 32;

    // load 32x256 comb tile (2048 float4, 8 per thread)
    #pragma unroll
    for (int u = 0; u < 8; ++u) {
        int idx = t + u * 256;
        int r = idx >> 6;      // 64 float4 per row
        int c4 = idx & 63;
        float4 v = make_float4(0.f, 0.f, 0.f, 0.f);
        if (row0 + r < N) v = *(const float4*)(comb + (size_t)(row0 + r) * 256 + c4 * 4);
        *(float4*)&c_lds[r][c4 * 4] = v;
    }
    __syncthreads();

    int cg = t & 31;   // column group (x4)
    int rg = t >> 5;   // row group (x4), 0..7
    float oacc[4][4];
    {
        float4 bb = *(const float4*)&b2[cg * 4];
        #pragma unroll
        for (int i = 0; i < 4; ++i) {
            oacc[i][0] = bb.x; oacc[i][1] = bb.y; oacc[i][2] = bb.z; oacc[i][3] = bb.w;
        }
    }

    for (int ch = 0; ch < 4; ++ch) {
        // ---- GEMM1 chunk: x[32][128] for hidden cols ch*128 + cg*4..+3 ----
        float f[4][4];
        {
            float4 bb = *(const float4*)&b1[ch * 128 + cg * 4];
            #pragma unroll
            for (int i = 0; i < 4; ++i) {
                f[i][0] = bb.x; f[i][1] = bb.y; f[i][2] = bb.z; f[i][3] = bb.w;
            }
        }
        for (int k = 0; k < 256; ++k) {
            float4 wv = *(const float4*)&W1[(size_t)k * 512 + ch * 128 + cg * 4];
            float a0 = c_lds[rg * 4 + 0][k];
            float a1 = c_lds[rg * 4 + 1][k];
            float a2 = c_lds[rg * 4 + 2][k];
            float a3 = c_lds[rg * 4 + 3][k];
            f[0][0] = fmaf(a0, wv.x, f[0][0]); f[0][1] = fmaf(a0, wv.y, f[0][1]);
            f[0][2] = fmaf(a0, wv.z, f[0][2]); f[0][3] = fmaf(a0, wv.w, f[0][3]);
            f[1][0] = fmaf(a1, wv.x, f[1][0]); f[1][1] = fmaf(a1, wv.y, f[1][1]);
            f[1][2] = fmaf(a1, wv.z, f[1][2]); f[1][3] = fmaf(a1, wv.w, f[1][3]);
            f[2][0] = fmaf(a2, wv.x, f[2][0]); f[2][1] = fmaf(a2, wv.y, f[2][1]);
            f[2][2] = fmaf(a2, wv.z, f[2][2]); f[2][3] = fmaf(a2, wv.w, f[2][3]);
            f[3][0] = fmaf(a3, wv.x, f[3][0]); f[3][1] = fmaf(a3, wv.y, f[3][1]);
            f[3][2] = fmaf(a3, wv.z, f[3][2]); f[3][3] = fmaf(a3, wv.w, f[3][3]);
        }
        #pragma unroll
        for (int i = 0; i < 4; ++i) {
            float4 g;
            g.x = gelu_exact(f[i][0]);
            g.y = gelu_exact(f[i][1]);
            g.z = gelu_exact(f[i][2]);
            g.w = gelu_exact(f[i][3]);
            *(float4*)&x_lds[rg * 4 + i][cg * 4] = g;
        }
        __syncthreads();
        // ---- GEMM2 accumulate: out += xg_chunk @ W2[ch*128..+127][:] ----
        for (int k = 0; k < 128; ++k) {
            float4 wv = *(const float4*)&W2[(size_t)(ch * 128 + k) * 128 + cg * 4];
            float a0 = x_lds[rg * 4 + 0][k];
            float a1 = x_lds[rg * 4 + 1][k];
            float a2 = x_lds[rg * 4 + 2][k];
            float a3 = x_lds[rg * 4 + 3][k];
            oacc[0][0] = fmaf(a0, wv.x, oacc[0][0]); oacc[0][1] = fmaf(a0, wv.y, oacc[0][1]);
            oacc[0][2] = fmaf(a0, wv.z, oacc[0][2]); oacc[0][3] = fmaf(a0, wv.w, oacc[0][3]);
            oacc[1][0] = fmaf(a1, wv.x, oacc[1][0]); oacc[1][1] = fmaf(a1, wv.y, oacc[1][1]);
            oacc[1][2] = fmaf(a1, wv.z, oacc[1][2]); oacc[1][3] = fmaf(a1, wv.w, oacc[1][3]);
            oacc[2][0] = fmaf(a2, wv.x, oacc[2][0]); oacc[2][1] = fmaf(a2, wv.y, oacc[2][1]);
            oacc[2][2] = fmaf(a2, wv.z, oacc[2][2]); oacc[2][3] = fmaf(a2, wv.w, oacc[2][3]);
            oacc[3][0] = fmaf(a3, wv.x, oacc[3][0]); oacc[3][1] = fmaf(a3, wv.y, oacc[3][1]);
            oacc[3][2] = fmaf(a3, wv.z, oacc[3][2]); oacc[3][3] = fmaf(a3, wv.w, oacc[3][3]);
        }
        __syncthreads();
    }
    #pragma unroll
    for (int i = 0; i < 4; ++i) {
        int r = row0 + rg * 4 + i;
        if (r < N) {
            float4 v = make_float4(oacc[i][0], oacc[i][1], oacc[i][2], oacc[i][3]);
            *(float4*)&out[(size_t)r * 128 + cg * 4] = v;
        }
    }
}

// ---------------------------------------------------------------------------
extern "C" void kernel_launch(void* const* d_in, const int* in_sizes, int n_in,
                              void* d_out, int out_size, void* d_ws, size_t ws_size,
                              hipStream_t stream)
{
    const float* h    = (const float*)d_in[0];
    const float* W_in = (const float*)d_in[1];
    const float* b_in = (const float*)d_in[2];
    const float* Wu   = (const float*)d_in[3];
    const float* bu   = (const float*)d_in[4];
    const float* Wv   = (const float*)d_in[5];
    const float* W1   = (const float*)d_in[6];
    const float* b1   = (const float*)d_in[7];
    const float* W2   = (const float*)d_in[8];
    const float* b2   = (const float*)d_in[9];
    const int*   src  = (const int*)d_in[10];
    const int*   dst  = (const int*)d_in[11];
    int N = in_sizes[0] / DIMM;
    int E = in_sizes[10];
    float* out = (float*)d_out;

    char* ws = (char*)d_ws;
    size_t off = 0;
    auto alloc = [&](size_t bytes) -> void* {
        void* p = ws + off;
        off = (off + bytes + 255) & ~(size_t)255;
        return p;
    };
    float* comb     = (float*)alloc((size_t)N * 256 * 4);
    float* attn_u   = (float*)alloc((size_t)N * 8 * 4);
    float* attn_v   = (float*)alloc((size_t)N * 8 * 4);
    int* row_ptr    = (int*)alloc((size_t)(N + 1) * 4);
    int* cursor     = (int*)alloc((size_t)N * 4);
    int* counts     = (int*)alloc((size_t)N * 4);
    int* src_sorted = (int*)alloc((size_t)E * 4);

    hipMemsetAsync(counts, 0, (size_t)N * 4, stream);
    k_h1<<<(N + 15) / 16, 256, 0, stream>>>(h, W_in, b_in, Wu, bu, Wv,
                                            comb, attn_u, attn_v, N);
    k_hist<<<(E + 255) / 256, 256, 0, stream>>>(dst, counts, E);
    k_scan<<<1, 1024, 0, stream>>>(counts, row_ptr, cursor, N, E);
    k_scatter<<<(E + 255) / 256, 256, 0, stream>>>(src, dst, cursor, src_sorted, E);
    k_agg<<<(N + 3) / 4, 256, 0, stream>>>(comb, attn_u, attn_v, row_ptr,
                                           src_sorted, comb, N);
    k_ff<<<(N + 31) / 32, 256, 0, stream>>>(comb, W1, b1, W2, b2, out, N);
}

// Round 2
// 537.636 us; speedup vs baseline: 1.5965x; 1.5965x over previous
//
#include <hip/hip_runtime.h>
#include <math.h>

#define DIMM 128
#define NHEAD 8

typedef __attribute__((ext_vector_type(8))) short bf16x8;
typedef __attribute__((ext_vector_type(4))) float f32x4;

__device__ __forceinline__ unsigned short f2bf(float x) {
    union { float f; unsigned int u; } v; v.f = x;
    unsigned int r = v.u + 0x7FFFu + ((v.u >> 16) & 1u);
    return (unsigned short)(r >> 16);
}
__device__ __forceinline__ float bf2f(unsigned short u) {
    union { unsigned int u; float f; } v; v.u = ((unsigned int)u) << 16;
    return v.f;
}
__device__ __forceinline__ float gelu_exact(float x) {
    return 0.5f * x * (1.0f + erff(x * 0.70710678118654752f));
}

// ---------------------------------------------------------------------------
// Kernel 1: h1 = h @ W_in + b_in  (f32 compute), write comb cols 0..127 (bf16)
// plus attn_u = h1@Wu+bu, attn_v = h1@Wv (f32)
// ---------------------------------------------------------------------------
__global__ __launch_bounds__(256) void k_h1(
        const float* __restrict__ h,
        const float* __restrict__ W_in, const float* __restrict__ b_in,
        const float* __restrict__ Wu, const float* __restrict__ bu,
        const float* __restrict__ Wv,
        unsigned short* __restrict__ comb,   // [N][256] bf16
        float* __restrict__ attn_u, float* __restrict__ attn_v,
        int N)
{
    __shared__ float h_lds[16][128];
    __shared__ float h1_lds[16][130];
    int t = threadIdx.x;
    int row0 = blockIdx.x * 16;

    #pragma unroll
    for (int u = 0; u < 2; ++u) {
        int idx = t + u * 256;
        int r = idx >> 5;
        int c4 = idx & 31;
        float4 v = make_float4(0.f, 0.f, 0.f, 0.f);
        if (row0 + r < N) v = *(const float4*)(h + (size_t)(row0 + r) * DIMM + c4 * 4);
        *(float4*)&h_lds[r][c4 * 4] = v;
    }
    __syncthreads();

    int col = t & 127;
    int rgrp = t >> 7;
    float acc[8];
    float bi = b_in[col];
    #pragma unroll
    for (int i = 0; i < 8; ++i) acc[i] = bi;
    for (int k = 0; k < 128; ++k) {
        float w = W_in[k * DIMM + col];
        #pragma unroll
        for (int i = 0; i < 8; ++i) acc[i] += h_lds[rgrp * 8 + i][k] * w;
    }
    #pragma unroll
    for (int i = 0; i < 8; ++i) {
        int r = rgrp * 8 + i;
        h1_lds[r][col] = acc[i];
        if (row0 + r < N) comb[(size_t)(row0 + r) * 256 + col] = f2bf(acc[i]);
    }
    __syncthreads();

    {
        int r = t >> 4;
        int j = t & 15;
        int head = j & 7;
        bool isv = (j >= 8);
        const float* W = isv ? Wv : Wu;
        float a = isv ? 0.f : bu[head];
        for (int k = 0; k < 128; ++k) a += h1_lds[r][k] * W[k * NHEAD + head];
        if (row0 + r < N) {
            if (isv) attn_v[(size_t)(row0 + r) * NHEAD + head] = a;
            else     attn_u[(size_t)(row0 + r) * NHEAD + head] = a;
        }
    }
}

// ---------------------------------------------------------------------------
// Weight prep: W1 [256][512] f32 -> W1T [512][256] bf16 ; W2 [512][128] f32 ->
// W2T [128][512] bf16 (B^T panels for MFMA B-fragments)
// ---------------------------------------------------------------------------
__global__ __launch_bounds__(256) void k_prep(
        const float* __restrict__ W1, const float* __restrict__ W2,
        unsigned short* __restrict__ W1T, unsigned short* __restrict__ W2T)
{
    int i = blockIdx.x * 256 + threadIdx.x;
    if (i < 256 * 512) {
        int k = i >> 9, j = i & 511;
        W1T[(size_t)j * 256 + k] = f2bf(W1[i]);
    }
    if (i < 512 * 128) {
        int k = i >> 7, j = i & 127;
        W2T[(size_t)j * 512 + k] = f2bf(W2[i]);
    }
}

// ---------------------------------------------------------------------------
// CSR build: histogram -> scan -> scatter
// ---------------------------------------------------------------------------
__global__ void k_hist(const int* __restrict__ dst, int* __restrict__ counts, int E) {
    int e = blockIdx.x * blockDim.x + threadIdx.x;
    if (e < E) atomicAdd(&counts[dst[e]], 1);
}

__global__ __launch_bounds__(1024) void k_scan(
        const int* __restrict__ counts,
        int* __restrict__ row_ptr, int* __restrict__ cursor, int N, int E)
{
    __shared__ int wsum[16];
    int t = threadIdx.x;
    int chunk = (N + 1023) / 1024;
    int s = t * chunk;
    int epos = min(s + chunk, N);
    int local = 0;
    for (int i = s; i < epos; ++i) local += counts[i];

    int lane = t & 63, w = t >> 6;
    int incl = local;
    #pragma unroll
    for (int d = 1; d < 64; d <<= 1) {
        int v = __shfl_up(incl, d, 64);
        if (lane >= d) incl += v;
    }
    if (lane == 63) wsum[w] = incl;
    __syncthreads();
    if (t == 0) {
        int run = 0;
        #pragma unroll
        for (int i = 0; i < 16; ++i) { int v = wsum[i]; wsum[i] = run; run += v; }
    }
    __syncthreads();
    int run = wsum[w] + incl - local;
    for (int i = s; i < epos; ++i) {
        row_ptr[i] = run;
        cursor[i] = run;
        run += counts[i];
    }
    if (t == 1023) row_ptr[N] = E;
}

__global__ void k_scatter(const int* __restrict__ src, const int* __restrict__ dst,
                          int* __restrict__ cursor, int* __restrict__ src_sorted, int E) {
    int e = blockIdx.x * blockDim.x + threadIdx.x;
    if (e < E) {
        int d = dst[e];
        int p = atomicAdd(&cursor[d], 1);
        src_sorted[p] = src[e];
    }
}

// ---------------------------------------------------------------------------
// per-dst-node online softmax + message aggregation (f32 math, bf16 h1 gather)
// ---------------------------------------------------------------------------
__device__ __forceinline__ float select8(const float v[8], int h) {
    float a = (h & 1) ? v[1] : v[0];
    float b = (h & 1) ? v[3] : v[2];
    float c = (h & 1) ? v[5] : v[4];
    float d = (h & 1) ? v[7] : v[6];
    float e = (h & 2) ? b : a;
    float f = (h & 2) ? d : c;
    return (h & 4) ? f : e;
}

__global__ __launch_bounds__(256) void k_agg(
        const unsigned short* __restrict__ comb_h1,   // [N][256] bf16, h1 = cols 0..127
        const float* __restrict__ attn_u, const float* __restrict__ attn_v,
        const int* __restrict__ row_ptr, const int* __restrict__ src_sorted,
        unsigned short* __restrict__ comb,            // msg -> cols 128..255
        int N)
{
    __shared__ float p_lds[4][64][8];
    __shared__ int   s_lds[4][64];
    int t = threadIdx.x;
    int w = t >> 6, lane = t & 63;
    int n = blockIdx.x * 4 + w;
    if (n >= N) return;
    int rs = row_ptr[n], re = row_ptr[n + 1];
    int deg = re - rs;
    unsigned short* msg_out = comb + (size_t)n * 256 + 128;
    if (deg == 0) {
        msg_out[lane] = 0;
        msg_out[64 + lane] = 0;
        return;
    }

    float av[8];
    {
        float4 a0 = *(const float4*)(attn_v + (size_t)n * 8);
        float4 a1 = *(const float4*)(attn_v + (size_t)n * 8 + 4);
        av[0] = a0.x; av[1] = a0.y; av[2] = a0.z; av[3] = a0.w;
        av[4] = a1.x; av[5] = a1.y; av[6] = a1.z; av[7] = a1.w;
    }
    int hsel = lane & 7;
    float m[8];
    #pragma unroll
    for (int hh = 0; hh < 8; ++hh) m[hh] = -3.0e38f;
    float m_sel = -3.0e38f, den_sel = 0.f, acc0 = 0.f, acc1 = 0.f;

    for (int base = 0; base < deg; base += 64) {
        int nact = min(64, deg - base);
        bool act = (lane < nact);
        int sn = act ? src_sorted[rs + base + lane] : 0;
        float sc[8];
        if (act) {
            float4 a0 = *(const float4*)(attn_u + (size_t)sn * 8);
            float4 a1 = *(const float4*)(attn_u + (size_t)sn * 8 + 4);
            float au[8] = {a0.x, a0.y, a0.z, a0.w, a1.x, a1.y, a1.z, a1.w};
            #pragma unroll
            for (int hh = 0; hh < 8; ++hh) {
                float v = au[hh] + av[hh];
                sc[hh] = (v >= 0.f) ? v : 0.2f * v;
            }
        } else {
            #pragma unroll
            for (int hh = 0; hh < 8; ++hh) sc[hh] = -3.0e38f;
        }
        float cm[8];
        #pragma unroll
        for (int hh = 0; hh < 8; ++hh) cm[hh] = sc[hh];
        #pragma unroll
        for (int d = 1; d < 64; d <<= 1) {
            #pragma unroll
            for (int hh = 0; hh < 8; ++hh)
                cm[hh] = fmaxf(cm[hh], __shfl_xor(cm[hh], d, 64));
        }
        float mn[8], p[8];
        #pragma unroll
        for (int hh = 0; hh < 8; ++hh) {
            mn[hh] = fmaxf(m[hh], cm[hh]);
            p[hh] = expf(sc[hh] - mn[hh]);
        }
        float csum[8];
        #pragma unroll
        for (int hh = 0; hh < 8; ++hh) csum[hh] = p[hh];
        #pragma unroll
        for (int d = 1; d < 64; d <<= 1) {
            #pragma unroll
            for (int hh = 0; hh < 8; ++hh)
                csum[hh] += __shfl_xor(csum[hh], d, 64);
        }
        float mn_sel = select8(mn, hsel);
        float scale_sel = expf(m_sel - mn_sel);
        float csum_sel = select8(csum, hsel);
        den_sel = den_sel * scale_sel + csum_sel;
        m_sel = mn_sel;
        #pragma unroll
        for (int hh = 0; hh < 8; ++hh) m[hh] = mn[hh];

        #pragma unroll
        for (int hh = 0; hh < 8; ++hh) p_lds[w][lane][hh] = p[hh];
        s_lds[w][lane] = sn;
        __threadfence_block();

        acc0 *= scale_sel;
        acc1 *= scale_sel;
        for (int j = 0; j < nact; ++j) {
            int sj = s_lds[w][j];
            float pj = p_lds[w][j][hsel];
            const unsigned short* hr = comb_h1 + (size_t)sj * 256;
            acc0 = fmaf(pj, bf2f(hr[lane]), acc0);
            acc1 = fmaf(pj, bf2f(hr[64 + lane]), acc1);
        }
    }
    float inv = 1.0f / den_sel;
    msg_out[lane] = f2bf(acc0 * inv);
    msg_out[64 + lane] = f2bf(acc1 * inv);
}

// ---------------------------------------------------------------------------
// Fused FF with bf16 MFMA:  out = gelu(comb @ W1 + b1) @ W2 + b2
// block = 256 threads (4 waves), 64 rows/block
// GEMM1: wave w -> hidden cols [w*128, w*128+128); A from LDS, B from W1T (L2)
// GEMM2: wave w -> out cols [w*32, w*32+32); A from LDS (gelu'd x), B from W2T
// ---------------------------------------------------------------------------
__global__ __launch_bounds__(256, 2) void k_ff(
        const unsigned short* __restrict__ comb,
        const unsigned short* __restrict__ W1T, const float* __restrict__ b1,
        const unsigned short* __restrict__ W2T, const float* __restrict__ b2,
        float* __restrict__ out, int N)
{
    __shared__ unsigned short smem[64 * 520];   // 66.6 KB, reused comb-tile -> x-tile
    int t = threadIdx.x;
    int lane = t & 63, w = t >> 6;
    int row0 = blockIdx.x * 64;
    const int g = lane >> 4, r16 = lane & 15;

    // load comb tile [64][256] bf16 -> smem row-stride 264 (bank-balanced)
    #pragma unroll
    for (int u = 0; u < 8; ++u) {
        int idx = t + u * 256;      // 0..2047, 16B chunks
        int r = idx >> 5, c8 = idx & 31;
        bf16x8 v = {0, 0, 0, 0, 0, 0, 0, 0};
        if (row0 + r < N)
            v = *(const bf16x8*)(comb + (size_t)(row0 + r) * 256 + c8 * 8);
        *(bf16x8*)&smem[r * 264 + c8 * 8] = v;
    }
    __syncthreads();

    // ---- GEMM1: [64][256] @ W1T panel -> wave-local hidden [64][128] ----
    f32x4 acc[4][8];
    #pragma unroll
    for (int mf = 0; mf < 4; ++mf)
        #pragma unroll
        for (int nf = 0; nf < 8; ++nf)
            acc[mf][nf] = (f32x4){0.f, 0.f, 0.f, 0.f};

    int wcol = w * 128;
    for (int ks = 0; ks < 256; ks += 32) {
        bf16x8 a[4], b[8];
        #pragma unroll
        for (int mf = 0; mf < 4; ++mf)
            a[mf] = *(const bf16x8*)&smem[(mf * 16 + r16) * 264 + ks + g * 8];
        #pragma unroll
        for (int nf = 0; nf < 8; ++nf)
            b[nf] = *(const bf16x8*)(W1T + (size_t)(wcol + nf * 16 + r16) * 256 + ks + g * 8);
        #pragma unroll
        for (int mf = 0; mf < 4; ++mf)
            #pragma unroll
            for (int nf = 0; nf < 8; ++nf)
                acc[mf][nf] = __builtin_amdgcn_mfma_f32_16x16x32_bf16(
                                  a[mf], b[nf], acc[mf][nf], 0, 0, 0);
    }
    __syncthreads();   // everyone done reading comb region

    // bias + gelu + bf16, write x tile [64][512] at row-stride 520
    #pragma unroll
    for (int nf = 0; nf < 8; ++nf) {
        int col = wcol + nf * 16 + r16;
        float bb = b1[col];
        #pragma unroll
        for (int mf = 0; mf < 4; ++mf) {
            #pragma unroll
            for (int q = 0; q < 4; ++q) {
                int row = mf * 16 + g * 4 + q;
                smem[row * 520 + col] = f2bf(gelu_exact(acc[mf][nf][q] + bb));
            }
        }
    }
    __syncthreads();

    // ---- GEMM2: x [64][512] @ W2T panel -> out cols [w*32, w*32+32) ----
    f32x4 acc2[4][2];
    #pragma unroll
    for (int mf = 0; mf < 4; ++mf)
        #pragma unroll
        for (int nf = 0; nf < 2; ++nf)
            acc2[mf][nf] = (f32x4){0.f, 0.f, 0.f, 0.f};

    int ocol = w * 32;
    for (int ks = 0; ks < 512; ks += 32) {
        bf16x8 a[4], b[2];
        #pragma unroll
        for (int mf = 0; mf < 4; ++mf)
            a[mf] = *(const bf16x8*)&smem[(mf * 16 + r16) * 520 + ks + g * 8];
        #pragma unroll
        for (int nf = 0; nf < 2; ++nf)
            b[nf] = *(const bf16x8*)(W2T + (size_t)(ocol + nf * 16 + r16) * 512 + ks + g * 8);
        #pragma unroll
        for (int mf = 0; mf < 4; ++mf)
            #pragma unroll
            for (int nf = 0; nf < 2; ++nf)
                acc2[mf][nf] = __builtin_amdgcn_mfma_f32_16x16x32_bf16(
                                   a[mf], b[nf], acc2[mf][nf], 0, 0, 0);
    }

    // epilogue: + b2, store f32
    #pragma unroll
    for (int nf = 0; nf < 2; ++nf) {
        int col = ocol + nf * 16 + r16;
        float bb = b2[col];
        #pragma unroll
        for (int mf = 0; mf < 4; ++mf) {
            #pragma unroll
            for (int q = 0; q < 4; ++q) {
                int row = row0 + mf * 16 + g * 4 + q;
                if (row < N)
                    out[(size_t)row * 128 + col] = acc2[mf][nf][q] + bb;
            }
        }
    }
}

// ---------------------------------------------------------------------------
extern "C" void kernel_launch(void* const* d_in, const int* in_sizes, int n_in,
                              void* d_out, int out_size, void* d_ws, size_t ws_size,
                              hipStream_t stream)
{
    const float* h    = (const float*)d_in[0];
    const float* W_in = (const float*)d_in[1];
    const float* b_in = (const float*)d_in[2];
    const float* Wu   = (const float*)d_in[3];
    const float* bu   = (const float*)d_in[4];
    const float* Wv   = (const float*)d_in[5];
    const float* W1   = (const float*)d_in[6];
    const float* b1   = (const float*)d_in[7];
    const float* W2   = (const float*)d_in[8];
    const float* b2   = (const float*)d_in[9];
    const int*   src  = (const int*)d_in[10];
    const int*   dst  = (const int*)d_in[11];
    int N = in_sizes[0] / DIMM;
    int E = in_sizes[10];
    float* out = (float*)d_out;

    char* ws = (char*)d_ws;
    size_t off = 0;
    auto alloc = [&](size_t bytes) -> void* {
        void* p = ws + off;
        off = (off + bytes + 255) & ~(size_t)255;
        return p;
    };
    unsigned short* comb = (unsigned short*)alloc((size_t)N * 256 * 2);
    float* attn_u   = (float*)alloc((size_t)N * 8 * 4);
    float* attn_v   = (float*)alloc((size_t)N * 8 * 4);
    int* row_ptr    = (int*)alloc((size_t)(N + 1) * 4);
    int* cursor     = (int*)alloc((size_t)N * 4);
    int* counts     = (int*)alloc((size_t)N * 4);
    int* src_sorted = (int*)alloc((size_t)E * 4);
    unsigned short* W1T = (unsigned short*)alloc((size_t)512 * 256 * 2);
    unsigned short* W2T = (unsigned short*)alloc((size_t)128 * 512 * 2);

    hipMemsetAsync(counts, 0, (size_t)N * 4, stream);
    k_prep<<<512, 256, 0, stream>>>(W1, W2, W1T, W2T);
    k_h1<<<(N + 15) / 16, 256, 0, stream>>>(h, W_in, b_in, Wu, bu, Wv,
                                            comb, attn_u, attn_v, N);
    k_hist<<<(E + 255) / 256, 256, 0, stream>>>(dst, counts, E);
    k_scan<<<1, 1024, 0, stream>>>(counts, row_ptr, cursor, N, E);
    k_scatter<<<(E + 255) / 256, 256, 0, stream>>>(src, dst, cursor, src_sorted, E);
    k_agg<<<(N + 3) / 4, 256, 0, stream>>>(comb, attn_u, attn_v, row_ptr,
                                           src_sorted, comb, N);
    k_ff<<<(N + 63) / 64, 256, 0, stream>>>(comb, W1T, b1, W2T, b2, out, N);
}